// Round 5
// baseline (1162.238 us; speedup 1.0000x reference)
//
#include <hip/hip_runtime.h>

#define T_LEN 4096
#define B_SZ  256

typedef float v2f __attribute__((ext_vector_type(2)));
typedef float v4f __attribute__((ext_vector_type(4)));

__device__ __forceinline__ float fexp2(float x) { return __builtin_amdgcn_exp2f(x); }
__device__ __forceinline__ float frcp(float x)  { return __builtin_amdgcn_rcpf(x); }

#define SB() __builtin_amdgcn_sched_barrier(0)

// DPP row_ror:S (S=1..15): lane l <- lane (l-S)&15 within its 16-lane row.
template<int S>
__device__ __forceinline__ float rorN(float v) {
    return __int_as_float(__builtin_amdgcn_update_dpp(
        0, __float_as_int(v), 0x120 + S, 0xf, 0xf, true));
}

// Inline-asm LOADS: RA cannot rematerialize an asm result (plain loads were
// re-emitted at uses, exposing full latency), and the asm vm stream keeps
// the outstanding-op counts for manual s_waitcnt exact.
template<int OFF>
__device__ __forceinline__ v4f aload(const float* p) {
    v4f r;
    asm volatile("global_load_dwordx4 %0, %1, off offset:%2"
                 : "=v"(r) : "v"(p), "i"(OFF) : "memory");
    return r;
}
__device__ __forceinline__ void aatomic(float* p, float v) {
    unsafeAtomicAdd(p, v);   // global_atomic_add_f32, no-return (result dead)
}

// ---------------------------------------------------------------------------
// Init: y1 <- bl1 broadcast, out <- bl2 broadcast. Recurrent kernels
// atomic-add their projected h contributions on top.
// ---------------------------------------------------------------------------
__global__ void init_bias_kernel(const float* __restrict__ bl1,
                                 const float* __restrict__ bl2,
                                 float* __restrict__ y1,
                                 float* __restrict__ out)
{
    const long idx = (long)blockIdx.x * blockDim.x + threadIdx.x; // over B*T
    float4 a1 = make_float4(bl1[0], bl1[1], bl1[2], bl1[3]);
    float4 b1 = make_float4(bl1[4], bl1[5], bl1[6], bl1[7]);
    float4 a2 = make_float4(bl2[0], bl2[1], bl2[2], bl2[3]);
    float4 b2 = make_float4(bl2[4], bl2[5], bl2[6], bl2[7]);
    float4* y4 = (float4*)y1;
    float4* o4 = (float4*)out;
    y4[idx * 2 + 0] = a1;
    y4[idx * 2 + 1] = b1;
    o4[idx * 2 + 0] = a2;
    o4[idx * 2 + 1] = b2;
}

// ---------------------------------------------------------------------------
// Recurrence, one direction (ST=+1 fwd / -1 bwd). 16 lanes per cell, 4 cells
// per wave, 128 blocks x 64 threads. Lane cl: unit j=cl&7, half=cl>>3.
// Each lane computes TWO gate rows packed <2 x float>: half0 -> (i_j, f_j),
// half1 -> (g_j, o_j). h is period-8 replicated over the 16-lane row; DPP
// row_ror does the h broadcast. x arrives through an asm-load register ring
// (3 macros of 4 steps), lookahead 2 macros, exact manual s_waitcnt
// vmcnt(N). Output projection fused as global_atomic_add_f32 of h_{t-1}
// from all lanes (Wc pre-halved; both halves contribute pa/2).
//
// THIS ROUND — hand software-pipelining of the step interior:
// measured 295 cyc/step ~ issue(146) + exposed trans-latency chain (~130).
// The scheduler provably (R2) does not hoist independent work into the
// transcendental stall windows, so we pin the schedule with
// sched_barrier(0) fences: the input-projection is pipelined ONE STEP
// AHEAD (step t computes ip for t+1) and split, together with the output
// projection, into three filler slabs placed exactly inside the three
// trans-latency gaps (after exp2(z-pair), after the sigmoid rcp pair,
// after exp2(sc)). Macro head computes ip for its first step (IPCOMP);
// step 4 runs without next-ip (next macro's ring regs are not yet
// vmcnt-waited). Memory-op order and the vmcnt ledger are unchanged.
// ---------------------------------------------------------------------------
template<int ST>
__device__ __forceinline__ void rec_body(
    const float* x,    // [B,T,8] layer input
    const float* Wih,  // [32,8]
    const float* Whh,  // [32,8]
    const float* bias, // [32]
    const float* Wp,   // [8,16] output linear
    int dcol,          // 0 fwd, 8 bwd
    float* y,          // [B,T,8], pre-inited with bias
    int b0)            // batch of first cell in this wave
{
    const int tid  = threadIdx.x;
    const int cl   = tid & 15;
    const int j    = cl & 7;
    const int half = cl >> 3;
    const int b    = b0 + (tid >> 4);

    const int rA = half * 16 + j;        // half0: i-row j   | half1: g-row 16+j
    const int rB = half * 16 + 8 + j;    // half0: f-row 8+j | half1: o-row 24+j

    const float NL2E = -1.4426950408889634f;
    const float GSC  = 2.0f * NL2E;
    const float sA   = half ? GSC : NL2E;     // g-row gets tanh pre-scale
    const float sB   = NL2E;
    // half0 vA = GSC*sigma(zi) (i pre-scaled for the sc-space c update);
    // half1 vA = tanh-core 2*sigma(2zg)-1
    const float aselA = half ? 2.0f : GSC;
    const float bselA = half ? -1.0f : 0.0f;

    // Per-lane constants: matvec weights permuted by rotation index.
    v2f Whk[8], Wik[8];
    float Wcp[8];
    #pragma unroll
    for (int s = 0; s < 8; ++s) {
        const int k = (j - s) & 7;
        Whk[s] = (v2f){Whh[rA * 8 + k] * sA, Whh[rB * 8 + k] * sB};
        Wcp[s] = Wp[j * 16 + dcol + k] * 0.5f;  // halved: both halves atomic
    }
    #pragma unroll
    for (int k = 0; k < 8; ++k)
        Wik[k] = (v2f){Wih[rA * 8 + k] * sA, Wih[rB * 8 + k] * sB};
    const v2f bpk = (v2f){bias[rA] * sA, bias[rB] * sB};

    const int start = (ST > 0) ? 0 : (T_LEN - 1);
    const float* xp = x + ((long)b * T_LEN + start) * 8;
    float*       wp = y + ((long)b * T_LEN + start) * 8 + j;

    float sc = 0.0f, h = 0.0f;           // sc = GSC * c
    v2f ipA_c = bpk, ipB_c = (v2f){0.0f, 0.0f};   // pipelined input proj

    // ip for the macro's FIRST step (also used at macro heads): 8 pk ops.
    auto ipcomp = [&](v4f xa, v4f xb) {
        v2f a = bpk;
        a = __builtin_elementwise_fma(Wik[0], (v2f){xa.x, xa.x}, a);
        a = __builtin_elementwise_fma(Wik[1], (v2f){xa.y, xa.y}, a);
        a = __builtin_elementwise_fma(Wik[2], (v2f){xa.z, xa.z}, a);
        a = __builtin_elementwise_fma(Wik[3], (v2f){xa.w, xa.w}, a);
        v2f q = Wik[4] * (v2f){xb.x, xb.x};
        q = __builtin_elementwise_fma(Wik[5], (v2f){xb.y, xb.y}, q);
        q = __builtin_elementwise_fma(Wik[6], (v2f){xb.z, xb.z}, q);
        q = __builtin_elementwise_fma(Wik[7], (v2f){xb.w, xb.w}, q);
        ipA_c = a; ipB_c = q;
    };

    // One pipelined step: consumes carried ip (this step's gates), computes
    // ip for the NEXT step from (nxa,nxb) inside the stall windows.
    auto stepP = [&](v4f nxa, v4f nxb, bool doProj, bool doNext) {
        // chain head: rotations + hidden matvec (4 depth-2 chains + tree)
        float hr0 = h;
        float hr1 = rorN<1>(h);
        float hr2 = rorN<2>(h);
        float hr3 = rorN<3>(h);
        float hr4 = rorN<4>(h);
        float hr5 = rorN<5>(h);
        float hr6 = rorN<6>(h);
        float hr7 = rorN<7>(h);

        v2f cA = __builtin_elementwise_fma(Whk[0], (v2f){hr0, hr0}, ipA_c);
        cA = __builtin_elementwise_fma(Whk[1], (v2f){hr1, hr1}, cA);
        v2f cB = __builtin_elementwise_fma(Whk[2], (v2f){hr2, hr2}, ipB_c);
        cB = __builtin_elementwise_fma(Whk[3], (v2f){hr3, hr3}, cB);
        v2f cC = Whk[4] * (v2f){hr4, hr4};
        cC = __builtin_elementwise_fma(Whk[5], (v2f){hr5, hr5}, cC);
        v2f cD = Whk[6] * (v2f){hr6, hr6};
        cD = __builtin_elementwise_fma(Whk[7], (v2f){hr7, hr7}, cD);
        const v2f z = (cA + cB) + (cC + cD);

        const float exA = fexp2(z.x);
        const float exB = fexp2(z.y);
        SB();
        // ---- FILLER 1 (covers exp2(z) latency): next-ip A-half + proj head
        v2f nA = bpk;
        float pa = 0.0f;
        if (doNext) {
            nA = __builtin_elementwise_fma(Wik[0], (v2f){nxa.x, nxa.x}, nA);
            nA = __builtin_elementwise_fma(Wik[1], (v2f){nxa.y, nxa.y}, nA);
            nA = __builtin_elementwise_fma(Wik[2], (v2f){nxa.z, nxa.z}, nA);
            nA = __builtin_elementwise_fma(Wik[3], (v2f){nxa.w, nxa.w}, nA);
        }
        if (doProj) {
            pa = hr0 * Wcp[0];
            pa = fmaf(hr1, Wcp[1], pa);
        }
        SB();
        const float rcA = frcp(1.0f + exA);
        const float rcB = frcp(1.0f + exB);
        SB();
        // ---- FILLER 2 (covers rcp latency): next-ip B-half + proj tail
        v2f nB = (v2f){0.0f, 0.0f};
        if (doNext) {
            nB = Wik[4] * (v2f){nxb.x, nxb.x};
            nB = __builtin_elementwise_fma(Wik[5], (v2f){nxb.y, nxb.y}, nB);
            nB = __builtin_elementwise_fma(Wik[6], (v2f){nxb.z, nxb.z}, nB);
            nB = __builtin_elementwise_fma(Wik[7], (v2f){nxb.w, nxb.w}, nB);
        }
        if (doProj) {
            pa = fmaf(hr2, Wcp[2], pa);
            pa = fmaf(hr3, Wcp[3], pa);
            pa = fmaf(hr4, Wcp[4], pa);
            pa = fmaf(hr5, Wcp[5], pa);
            pa = fmaf(hr6, Wcp[6], pa);
            pa = fmaf(hr7, Wcp[7], pa);
            aatomic(wp, pa);
            wp += ST * 8;
        }
        SB();
        // activations: half0 vA = GSC*sigma(zi), half1 vA = tanh(zg);
        //              half0 vB = sigma(zf),     half1 vB = sigma(zo)
        const float vA = fmaf(rcA, aselA, bselA);
        const float vB = rcB;
        // cross-half exchange (row_ror:8 swaps the 8-lane halves);
        // i*g product is vA*ror8(vA) on BOTH halves (no select needed)
        const float pAx = rorN<8>(vA);
        const float pBx = rorN<8>(vB);
        const float gf = half ? pBx : vB;
        const float go = half ? vB  : pBx;
        sc = fmaf(gf, sc, vA * pAx);            // sc = GSC * c
        const float e2 = fexp2(sc);
        SB();
        // ---- FILLER 3 (covers exp2(sc) latency): commit carried ip
        if (doNext) { ipA_c = nA; ipB_c = nB; }
        SB();
        const float r2 = frcp(1.0f + e2);
        const float th = fmaf(r2, 2.0f, -1.0f);
        h = go * th;
    };

    // Named prefetch ring: 3 macros x 4 steps (2 x v4f per step).
    v4f A0, A1, A2, A3, A4, A5, A6, A7;
    v4f B0, B1, B2, B3, B4, B5, B6, B7;
    v4f C0, C1, C2, C3, C4, C5, C6, C7;

#define AREGS A0, A1, A2, A3, A4, A5, A6, A7
#define BREGS B0, B1, B2, B3, B4, B5, B6, B7
#define CREGS C0, C1, C2, C3, C4, C5, C6, C7

// Inner 8-parameter macros + one indirection layer so that a register-set
// macro (AREGS/BREGS/CREGS) expands to 8 arguments before re-scanning.
#define LOADM_I(P0, P1, P2, P3, P4, P5, P6, P7)                                \
    P0 = aload<0>(xp);            P1 = aload<16>(xp);                          \
    P2 = aload<ST * 32>(xp);      P3 = aload<ST * 32 + 16>(xp);                \
    P4 = aload<ST * 64>(xp);      P5 = aload<ST * 64 + 16>(xp);                \
    P6 = aload<ST * 96>(xp);      P7 = aload<ST * 96 + 16>(xp);                \
    xp += ST * 32;
#define LOADM(REGS) LOADM_I(REGS)

#define WAITM_I(N, P0, P1, P2, P3, P4, P5, P6, P7)                             \
    asm volatile("s_waitcnt vmcnt(" #N ")"                                     \
        : "+v"(P0), "+v"(P1), "+v"(P2), "+v"(P3),                              \
          "+v"(P4), "+v"(P5), "+v"(P6), "+v"(P7) :: "memory")
#define WAITM(N, REGS) WAITM_I(N, REGS)

// Pipelined macro: ip for step1 computed at head; steps 1-3 compute the
// next step's ip in their stall windows; step 4 has no safe next-x (next
// macro's regs not yet waited) and runs proj-only fillers.
#define MACRO4_I(P0, P1, P2, P3, P4, P5, P6, P7, FIRSTPROJ)                    \
    ipcomp(P0, P1);                                                            \
    stepP(P2, P3, FIRSTPROJ, true);                                            \
    stepP(P4, P5, true, true);                                                 \
    stepP(P6, P7, true, true);                                                 \
    stepP(P6, P7, true, false);
#define MACRO4(REGS, FIRSTPROJ) MACRO4_I(REGS, FIRSTPROJ)

    // drain compiler-issued (weight) loads so asm vm counts are exact
    asm volatile("s_waitcnt vmcnt(0)" ::: "memory");

    LOADM(AREGS)                       // L0
    LOADM(BREGS)                       // L1
    LOADM(CREGS)                       // L2
    WAITM(16, AREGS); MACRO4(AREGS, false)    // M0 (3 atomics: h_{-1}=0)
    LOADM(AREGS)                       // L3
    WAITM(19, BREGS); MACRO4(BREGS, true)     // M1 (4 atomics)
    LOADM(BREGS)                       // L4
    WAITM(23, CREGS); MACRO4(CREGS, true)     // M2

    for (int i = 0; i < 339; ++i) {    // M3..M1019, loads L5..L1021
        LOADM(CREGS) WAITM(24, AREGS); MACRO4(AREGS, true)
        LOADM(AREGS) WAITM(24, BREGS); MACRO4(BREGS, true)
        LOADM(BREGS) WAITM(24, CREGS); MACRO4(CREGS, true)
    }
    LOADM(CREGS)                       // L1022
    WAITM(24, AREGS); MACRO4(AREGS, true)     // M1020
    LOADM(AREGS)                       // L1023
    WAITM(24, BREGS); MACRO4(BREGS, true)     // M1021
    WAITM(16, CREGS); MACRO4(CREGS, true)     // M1022
    WAITM(8,  AREGS); MACRO4(AREGS, true)     // M1023

#undef LOADM
#undef LOADM_I
#undef MACRO4
#undef MACRO4_I
#undef WAITM
#undef WAITM_I
#undef AREGS
#undef BREGS
#undef CREGS

    // tail: projection of the final h (all lanes, halved Wcp)
    {
        float pa = h * Wcp[0];
        pa = fmaf(rorN<1>(h), Wcp[1], pa);
        pa = fmaf(rorN<2>(h), Wcp[2], pa);
        pa = fmaf(rorN<3>(h), Wcp[3], pa);
        pa = fmaf(rorN<4>(h), Wcp[4], pa);
        pa = fmaf(rorN<5>(h), Wcp[5], pa);
        pa = fmaf(rorN<6>(h), Wcp[6], pa);
        pa = fmaf(rorN<7>(h), Wcp[7], pa);
        aatomic(wp, pa);
    }
}

__global__ __launch_bounds__(64, 1)
void lstm_rec_kernel(const float* __restrict__ x,
                     const float* __restrict__ WihF, const float* __restrict__ WhhF,
                     const float* __restrict__ bF,
                     const float* __restrict__ WihB, const float* __restrict__ WhhB,
                     const float* __restrict__ bB,
                     const float* __restrict__ Wp,
                     float* __restrict__ y)
{
    if (blockIdx.x < 64)
        rec_body<1 >(x, WihF, WhhF, bF, Wp, 0, y, 4 * (int)blockIdx.x);
    else
        rec_body<-1>(x, WihB, WhhB, bB, Wp, 8, y, 4 * ((int)blockIdx.x - 64));
}

extern "C" void kernel_launch(void* const* d_in, const int* in_sizes, int n_in,
                              void* d_out, int out_size, void* d_ws, size_t ws_size,
                              hipStream_t stream)
{
    const float* x     = (const float*)d_in[0];
    const float* Wih1f = (const float*)d_in[1];
    const float* Whh1f = (const float*)d_in[2];
    const float* b1f   = (const float*)d_in[3];
    const float* Wih1b = (const float*)d_in[4];
    const float* Whh1b = (const float*)d_in[5];
    const float* b1b   = (const float*)d_in[6];
    const float* Wih2f = (const float*)d_in[7];
    const float* Whh2f = (const float*)d_in[8];
    const float* b2f   = (const float*)d_in[9];
    const float* Wih2b = (const float*)d_in[10];
    const float* Whh2b = (const float*)d_in[11];
    const float* b2b   = (const float*)d_in[12];
    const float* W1    = (const float*)d_in[13];
    const float* bl1   = (const float*)d_in[14];
    const float* W2    = (const float*)d_in[15];
    const float* bl2   = (const float*)d_in[16];

    float* out = (float*)d_out;
    float* y1  = (float*)d_ws;   // [B,T,8] fp32 = 32 MB (proven-safe ws budget)

    const int BT = B_SZ * T_LEN;

    init_bias_kernel<<<BT / 256, 256, 0, stream>>>(bl1, bl2, y1, out);

    lstm_rec_kernel<<<128, 64, 0, stream>>>(x, Wih1f, Whh1f, b1f,
                                            Wih1b, Whh1b, b1b, W1, y1);

    lstm_rec_kernel<<<128, 64, 0, stream>>>(y1, Wih2f, Whh2f, b2f,
                                            Wih2b, Whh2b, b2b, W2, out);
}

// Round 6
// 1070.927 us; speedup vs baseline: 1.0853x; 1.0853x over previous
//
#include <hip/hip_runtime.h>

#define T_LEN 4096
#define B_SZ  256

typedef float v2f __attribute__((ext_vector_type(2)));
typedef float v4f __attribute__((ext_vector_type(4)));

__device__ __forceinline__ float fexp2(float x) { return __builtin_amdgcn_exp2f(x); }
__device__ __forceinline__ float frcp(float x)  { return __builtin_amdgcn_rcpf(x); }

// DPP row_ror:S (S=1..15): lane l <- lane (l-S)&15 within its 16-lane row.
template<int S>
__device__ __forceinline__ float rorN(float v) {
    return __int_as_float(__builtin_amdgcn_update_dpp(
        0, __float_as_int(v), 0x120 + S, 0xf, 0xf, true));
}

// Inline-asm vm ops: RA cannot rematerialize an asm result (plain loads were
// re-emitted at uses, exposing full latency), and the asm vm stream keeps
// the outstanding-op counts for manual s_waitcnt exact.
template<int OFF>
__device__ __forceinline__ v4f aload(const float* p) {
    v4f r;
    asm volatile("global_load_dwordx4 %0, %1, off offset:%2"
                 : "=v"(r) : "v"(p), "i"(OFF) : "memory");
    return r;
}
__device__ __forceinline__ void aatomic(float* p, float v) {
    unsafeAtomicAdd(p, v);   // global_atomic_add_f32, no-return (result dead)
}
__device__ __forceinline__ void astore(float* p, float v) {
    asm volatile("global_store_dword %0, %1, off" :: "v"(p), "v"(v) : "memory");
}

// ---------------------------------------------------------------------------
// Fallback-path init: y1 <- bl1 broadcast, out <- bl2 broadcast.
// ---------------------------------------------------------------------------
__global__ void init_bias_kernel(const float* __restrict__ bl1,
                                 const float* __restrict__ bl2,
                                 float* __restrict__ y1,
                                 float* __restrict__ out)
{
    const long idx = (long)blockIdx.x * blockDim.x + threadIdx.x; // over B*T
    float4 a1 = make_float4(bl1[0], bl1[1], bl1[2], bl1[3]);
    float4 b1 = make_float4(bl1[4], bl1[5], bl1[6], bl1[7]);
    float4 a2 = make_float4(bl2[0], bl2[1], bl2[2], bl2[3]);
    float4 b2 = make_float4(bl2[4], bl2[5], bl2[6], bl2[7]);
    float4* y4 = (float4*)y1;
    float4* o4 = (float4*)out;
    y4[idx * 2 + 0] = a1;
    y4[idx * 2 + 1] = b1;
    o4[idx * 2 + 0] = a2;
    o4[idx * 2 + 1] = b2;
}

// ---------------------------------------------------------------------------
// Big-ws path: dense output projection y[b,t,:] = Hf@Wf^T + Hb@Wb^T + bl.
// One thread per (b,t) row. Hb/yo may ALIAS (final kernel runs in-place over
// d_out) -> no __restrict__ on those two; loads are emitted before stores.
// Memory-bound: ~96 MB traffic ~ 18 us.
// ---------------------------------------------------------------------------
__global__ void proj_kernel(const float* __restrict__ Hf,
                            const float* Hb,
                            const float* __restrict__ W,   // [8,16]
                            const float* __restrict__ bl,  // [8]
                            float* yo)
{
    const long idx = (long)blockIdx.x * blockDim.x + threadIdx.x; // over B*T
    const float4* f4 = (const float4*)(Hf + idx * 8);
    const float4* b4 = (const float4*)(Hb + idx * 8);
    float4 fa = f4[0], fb = f4[1];
    float4 ba = b4[0], bb = b4[1];
    float o[8];
    #pragma unroll
    for (int d = 0; d < 8; ++d) {
        float s = bl[d];
        s = fmaf(fa.x, W[d * 16 + 0], s);
        s = fmaf(fa.y, W[d * 16 + 1], s);
        s = fmaf(fa.z, W[d * 16 + 2], s);
        s = fmaf(fa.w, W[d * 16 + 3], s);
        s = fmaf(fb.x, W[d * 16 + 4], s);
        s = fmaf(fb.y, W[d * 16 + 5], s);
        s = fmaf(fb.z, W[d * 16 + 6], s);
        s = fmaf(fb.w, W[d * 16 + 7], s);
        s = fmaf(ba.x, W[d * 16 + 8], s);
        s = fmaf(ba.y, W[d * 16 + 9], s);
        s = fmaf(ba.z, W[d * 16 + 10], s);
        s = fmaf(ba.w, W[d * 16 + 11], s);
        s = fmaf(bb.x, W[d * 16 + 12], s);
        s = fmaf(bb.y, W[d * 16 + 13], s);
        s = fmaf(bb.z, W[d * 16 + 14], s);
        s = fmaf(bb.w, W[d * 16 + 15], s);
        o[d] = s;
    }
    float4* y4 = (float4*)(yo + idx * 8);
    y4[0] = make_float4(o[0], o[1], o[2], o[3]);
    y4[1] = make_float4(o[4], o[5], o[6], o[7]);
}

// ---------------------------------------------------------------------------
// Recurrence, one direction (ST=+1 fwd / -1 bwd). 16 lanes per cell, 4 cells
// per wave, 128 blocks x 64 threads. Lane cl: unit j=cl&7, half=cl>>3.
// Each lane computes TWO gate rows packed <2 x float>: half0 -> (i_j, f_j),
// half1 -> (g_j, o_j). h is period-8 replicated over the 16-lane row; DPP
// row_ror does the h broadcast. x arrives through an asm-load register ring
// (3 macros of 4 steps), lookahead 2 macros, exact manual s_waitcnt vmcnt(N).
//
// PROJ=true  (fallback, proven): output projection fused as atomic-add of
//   h_{t-1} from all lanes (Wc pre-halved), vmcnt ramp 16/19/23, steady 24,
//   tail projects the final h.
// PROJ=false (this round):  the projection block (8 fma + atomic, ~16-18
//   issue cyc/step) is DELETED from the serial stream; instead each step
//   ends with ONE plain global_store_dword of h_t. h is replicated in both
//   halves, so 2 lanes/address store IDENTICAL data -> benign duplicate, no
//   exec mask needed. No atomics anywhere. vmcnt ledger re-derived for
//   4 stores EVERY macro: ramp 16/20/24, steady 24, epilogue 24/24/16/8,
//   no tail (step t stores h_t directly).
// ---------------------------------------------------------------------------
template<int ST, bool PROJ>
__device__ __forceinline__ void rec_body(
    const float* x,    // [B,T,8] layer input
    const float* Wih,  // [32,8]
    const float* Whh,  // [32,8]
    const float* bias, // [32]
    const float* Wp,   // [8,16] output linear (PROJ only)
    int dcol,          // 0 fwd, 8 bwd       (PROJ only)
    float* y,          // [B,T,8] pre-inited (PROJ only)
    float* H,          // [B,T,8] h sequence (!PROJ only)
    int b0)            // batch of first cell in this wave
{
    const int tid  = threadIdx.x;
    const int cl   = tid & 15;
    const int j    = cl & 7;
    const int half = cl >> 3;
    const int b    = b0 + (tid >> 4);

    const int rA = half * 16 + j;        // half0: i-row j   | half1: g-row 16+j
    const int rB = half * 16 + 8 + j;    // half0: f-row 8+j | half1: o-row 24+j

    const float NL2E = -1.4426950408889634f;
    const float GSC  = 2.0f * NL2E;
    const float sA   = half ? GSC : NL2E;     // g-row gets tanh pre-scale
    const float sB   = NL2E;
    // half0 vA = GSC*sigma(zi) (i pre-scaled for the sc-space c update);
    // half1 vA = tanh-core 2*sigma(2zg)-1
    const float aselA = half ? 2.0f : GSC;
    const float bselA = half ? -1.0f : 0.0f;

    // Per-lane constants: matvec weights permuted by rotation index.
    v2f Whk[8], Wik[8];
    float Wcp[8];
    #pragma unroll
    for (int s = 0; s < 8; ++s) {
        const int k = (j - s) & 7;
        Whk[s] = (v2f){Whh[rA * 8 + k] * sA, Whh[rB * 8 + k] * sB};
        if constexpr (PROJ)
            Wcp[s] = Wp[j * 16 + dcol + k] * 0.5f;  // halved: both halves atomic
    }
    #pragma unroll
    for (int k = 0; k < 8; ++k)
        Wik[k] = (v2f){Wih[rA * 8 + k] * sA, Wih[rB * 8 + k] * sB};
    const v2f bpk = (v2f){bias[rA] * sA, bias[rB] * sB};

    const int start = (ST > 0) ? 0 : (T_LEN - 1);
    const float* xp = x + ((long)b * T_LEN + start) * 8;
    float* wp = nullptr;
    float* hp = nullptr;
    if constexpr (PROJ)  wp = y + ((long)b * T_LEN + start) * 8 + j;
    if constexpr (!PROJ) hp = H + ((long)b * T_LEN + start) * 8 + j;

    float sc = 0.0f, h = 0.0f;   // sc = GSC * c

    auto step = [&](v4f xa, v4f xb, bool doProj) {
        // input projection partials, two independent seeds (no h dependence)
        v2f ipA = bpk;
        ipA = __builtin_elementwise_fma(Wik[0], (v2f){xa.x, xa.x}, ipA);
        ipA = __builtin_elementwise_fma(Wik[1], (v2f){xa.y, xa.y}, ipA);
        ipA = __builtin_elementwise_fma(Wik[2], (v2f){xa.z, xa.z}, ipA);
        ipA = __builtin_elementwise_fma(Wik[3], (v2f){xa.w, xa.w}, ipA);
        v2f ipB = Wik[4] * (v2f){xb.x, xb.x};
        ipB = __builtin_elementwise_fma(Wik[5], (v2f){xb.y, xb.y}, ipB);
        ipB = __builtin_elementwise_fma(Wik[6], (v2f){xb.z, xb.z}, ipB);
        ipB = __builtin_elementwise_fma(Wik[7], (v2f){xb.w, xb.w}, ipB);

        // 7 independent VALU rotations of h (h_{t-1})
        float hr0 = h;
        float hr1 = rorN<1>(h);
        float hr2 = rorN<2>(h);
        float hr3 = rorN<3>(h);
        float hr4 = rorN<4>(h);
        float hr5 = rorN<5>(h);
        float hr6 = rorN<6>(h);
        float hr7 = rorN<7>(h);

        // hidden matvec: 4 depth-2 chains + depth-2 add tree
        v2f cA = __builtin_elementwise_fma(Whk[0], (v2f){hr0, hr0}, ipA);
        cA = __builtin_elementwise_fma(Whk[1], (v2f){hr1, hr1}, cA);
        v2f cB = __builtin_elementwise_fma(Whk[2], (v2f){hr2, hr2}, ipB);
        cB = __builtin_elementwise_fma(Whk[3], (v2f){hr3, hr3}, cB);
        v2f cC = Whk[4] * (v2f){hr4, hr4};
        cC = __builtin_elementwise_fma(Whk[5], (v2f){hr5, hr5}, cC);
        v2f cD = Whk[6] * (v2f){hr6, hr6};
        cD = __builtin_elementwise_fma(Whk[7], (v2f){hr7, hr7}, cD);
        const v2f z = (cA + cB) + (cC + cD);

        // fused output projection of h_{t-1} (fallback path only)
        if constexpr (PROJ) {
            if (doProj) {
                float pa = hr0 * Wcp[0];
                pa = fmaf(hr1, Wcp[1], pa);
                pa = fmaf(hr2, Wcp[2], pa);
                pa = fmaf(hr3, Wcp[3], pa);
                pa = fmaf(hr4, Wcp[4], pa);
                pa = fmaf(hr5, Wcp[5], pa);
                pa = fmaf(hr6, Wcp[6], pa);
                pa = fmaf(hr7, Wcp[7], pa);
                aatomic(wp, pa);
                wp += ST * 8;
            }
        }

        // activations: half0 vA = GSC*sigma(zi), half1 vA = tanh(zg);
        //              half0 vB = sigma(zf),     half1 vB = sigma(zo)
        const float vA = fmaf(frcp(1.0f + fexp2(z.x)), aselA, bselA);
        const float vB = frcp(1.0f + fexp2(z.y));

        // cross-half gate exchange (row_ror:8 swaps the two 8-lane halves);
        // i*g product is vA*ror8(vA) on BOTH halves (no select needed)
        const float pAx = rorN<8>(vA);
        const float pBx = rorN<8>(vB);
        const float gf = half ? pBx : vB;
        const float go = half ? vB  : pBx;

        sc = fmaf(gf, sc, vA * pAx);            // sc = GSC * c
        const float th = fmaf(frcp(1.0f + fexp2(sc)), 2.0f, -1.0f);
        h = go * th;

        // big-ws path: store h_t (both halves store identical value to the
        // same address -> benign duplicate; 1 vm op/step for the ledger)
        if constexpr (!PROJ) {
            astore(hp, h);
            hp += ST * 8;
        }
    };

    // Named prefetch ring: 3 macros x 4 steps (2 x v4f per step).
    v4f A0, A1, A2, A3, A4, A5, A6, A7;
    v4f B0, B1, B2, B3, B4, B5, B6, B7;
    v4f C0, C1, C2, C3, C4, C5, C6, C7;

#define AREGS A0, A1, A2, A3, A4, A5, A6, A7
#define BREGS B0, B1, B2, B3, B4, B5, B6, B7
#define CREGS C0, C1, C2, C3, C4, C5, C6, C7

// Inner 8-parameter macros + one indirection layer so that a register-set
// macro (AREGS/BREGS/CREGS) expands to 8 arguments before re-scanning.
#define LOADM_I(P0, P1, P2, P3, P4, P5, P6, P7)                                \
    P0 = aload<0>(xp);            P1 = aload<16>(xp);                          \
    P2 = aload<ST * 32>(xp);      P3 = aload<ST * 32 + 16>(xp);                \
    P4 = aload<ST * 64>(xp);      P5 = aload<ST * 64 + 16>(xp);                \
    P6 = aload<ST * 96>(xp);      P7 = aload<ST * 96 + 16>(xp);                \
    xp += ST * 32;
#define LOADM(REGS) LOADM_I(REGS)

#define WAITM_I(N, P0, P1, P2, P3, P4, P5, P6, P7)                             \
    asm volatile("s_waitcnt vmcnt(" #N ")"                                     \
        : "+v"(P0), "+v"(P1), "+v"(P2), "+v"(P3),                              \
          "+v"(P4), "+v"(P5), "+v"(P6), "+v"(P7) :: "memory")
#define WAITM(N, REGS) WAITM_I(N, REGS)

#define MACRO4_I(P0, P1, P2, P3, P4, P5, P6, P7, FIRSTPROJ)                    \
    step(P0, P1, FIRSTPROJ);                                                   \
    step(P2, P3, true);                                                        \
    step(P4, P5, true);                                                        \
    step(P6, P7, true);
#define MACRO4(REGS, FIRSTPROJ) MACRO4_I(REGS, FIRSTPROJ)

    // drain compiler-issued (weight) loads so asm vm counts are exact
    asm volatile("s_waitcnt vmcnt(0)" ::: "memory");

    LOADM(AREGS)                       // L0
    LOADM(BREGS)                       // L1
    LOADM(CREGS)                       // L2

    if constexpr (PROJ) {
        // atomics enter the stream 3, +4, +4 (first step skips: h_{-1}=0)
        WAITM(16, AREGS); MACRO4(AREGS, false)    // M0
        LOADM(AREGS)                   // L3
        WAITM(19, BREGS); MACRO4(BREGS, true)     // M1
        LOADM(BREGS)                   // L4
        WAITM(23, CREGS); MACRO4(CREGS, true)     // M2
    } else {
        // stores enter the stream 4, 4, 4 (every step stores h_t)
        WAITM(16, AREGS); MACRO4(AREGS, true)     // M0
        LOADM(AREGS)                   // L3
        WAITM(20, BREGS); MACRO4(BREGS, true)     // M1
        LOADM(BREGS)                   // L4
        WAITM(24, CREGS); MACRO4(CREGS, true)     // M2
    }

    for (int i = 0; i < 339; ++i) {    // M3..M1019, loads L5..L1021
        LOADM(CREGS) WAITM(24, AREGS); MACRO4(AREGS, true)
        LOADM(AREGS) WAITM(24, BREGS); MACRO4(BREGS, true)
        LOADM(BREGS) WAITM(24, CREGS); MACRO4(CREGS, true)
    }
    LOADM(CREGS)                       // L1022
    WAITM(24, AREGS); MACRO4(AREGS, true)     // M1020
    LOADM(AREGS)                       // L1023
    WAITM(24, BREGS); MACRO4(BREGS, true)     // M1021
    WAITM(16, CREGS); MACRO4(CREGS, true)     // M1022
    WAITM(8,  AREGS); MACRO4(AREGS, true)     // M1023

#undef LOADM
#undef LOADM_I
#undef MACRO4
#undef MACRO4_I
#undef WAITM
#undef WAITM_I
#undef AREGS
#undef BREGS
#undef CREGS

    // tail: projection of the final h (fallback path only; the store path
    // already wrote h_t inside every step)
    if constexpr (PROJ) {
        float pa = h * Wcp[0];
        pa = fmaf(rorN<1>(h), Wcp[1], pa);
        pa = fmaf(rorN<2>(h), Wcp[2], pa);
        pa = fmaf(rorN<3>(h), Wcp[3], pa);
        pa = fmaf(rorN<4>(h), Wcp[4], pa);
        pa = fmaf(rorN<5>(h), Wcp[5], pa);
        pa = fmaf(rorN<6>(h), Wcp[6], pa);
        pa = fmaf(rorN<7>(h), Wcp[7], pa);
        aatomic(wp, pa);
    }
}

__global__ __launch_bounds__(64, 1)
void lstm_rec_kernel(const float* __restrict__ x,
                     const float* __restrict__ WihF, const float* __restrict__ WhhF,
                     const float* __restrict__ bF,
                     const float* __restrict__ WihB, const float* __restrict__ WhhB,
                     const float* __restrict__ bB,
                     const float* __restrict__ Wp,
                     float* __restrict__ y)
{
    if (blockIdx.x < 64)
        rec_body<1,  true>(x, WihF, WhhF, bF, Wp, 0, y, nullptr, 4 * (int)blockIdx.x);
    else
        rec_body<-1, true>(x, WihB, WhhB, bB, Wp, 8, y, nullptr, 4 * ((int)blockIdx.x - 64));
}

__global__ __launch_bounds__(64, 1)
void lstm_rec_np_kernel(const float* __restrict__ x,
                        const float* __restrict__ WihF, const float* __restrict__ WhhF,
                        const float* __restrict__ bF,
                        const float* __restrict__ WihB, const float* __restrict__ WhhB,
                        const float* __restrict__ bB,
                        float* __restrict__ Hf,
                        float* __restrict__ Hb)
{
    if (blockIdx.x < 64)
        rec_body<1,  false>(x, WihF, WhhF, bF, nullptr, 0, nullptr, Hf, 4 * (int)blockIdx.x);
    else
        rec_body<-1, false>(x, WihB, WhhB, bB, nullptr, 0, nullptr, Hb, 4 * ((int)blockIdx.x - 64));
}

extern "C" void kernel_launch(void* const* d_in, const int* in_sizes, int n_in,
                              void* d_out, int out_size, void* d_ws, size_t ws_size,
                              hipStream_t stream)
{
    const float* x     = (const float*)d_in[0];
    const float* Wih1f = (const float*)d_in[1];
    const float* Whh1f = (const float*)d_in[2];
    const float* b1f   = (const float*)d_in[3];
    const float* Wih1b = (const float*)d_in[4];
    const float* Whh1b = (const float*)d_in[5];
    const float* b1b   = (const float*)d_in[6];
    const float* Wih2f = (const float*)d_in[7];
    const float* Whh2f = (const float*)d_in[8];
    const float* b2f   = (const float*)d_in[9];
    const float* Wih2b = (const float*)d_in[10];
    const float* Whh2b = (const float*)d_in[11];
    const float* b2b   = (const float*)d_in[12];
    const float* W1    = (const float*)d_in[13];
    const float* bl1   = (const float*)d_in[14];
    const float* W2    = (const float*)d_in[15];
    const float* bl2   = (const float*)d_in[16];

    float* out = (float*)d_out;
    const int BT = B_SZ * T_LEN;
    const size_t MB32 = (size_t)32 * 1024 * 1024;

    if (ws_size >= 2 * MB32) {
        // Big-ws path: rec kernels store raw h; projections are separate
        // memory-bound kernels. d_out is borrowed for the backward-H buffer
        // (dead by the time the final in-place proj overwrites it).
        float* ws0 = (float*)d_ws;                  // H1f, then H2f (32 MB)
        float* ws1 = (float*)((char*)d_ws + MB32);  // y1             (32 MB)
        float* Hb  = out;                           // H1b, then H2b  (borrow)

        lstm_rec_np_kernel<<<128, 64, 0, stream>>>(x, Wih1f, Whh1f, b1f,
                                                   Wih1b, Whh1b, b1b, ws0, Hb);
        proj_kernel<<<BT / 256, 256, 0, stream>>>(ws0, Hb, W1, bl1, ws1);   // y1
        lstm_rec_np_kernel<<<128, 64, 0, stream>>>(ws1, Wih2f, Whh2f, b2f,
                                                   Wih2b, Whh2b, b2b, ws0, Hb);
        proj_kernel<<<BT / 256, 256, 0, stream>>>(ws0, Hb, W2, bl2, out);   // in-place
    } else {
        // Proven fallback (1098 us): fused atomic projection.
        float* y1 = (float*)d_ws;   // 32 MB

        init_bias_kernel<<<BT / 256, 256, 0, stream>>>(bl1, bl2, y1, out);
        lstm_rec_kernel<<<128, 64, 0, stream>>>(x, Wih1f, Whh1f, b1f,
                                                Wih1b, Whh1b, b1b, W1, y1);
        lstm_rec_kernel<<<128, 64, 0, stream>>>(y1, Wih2f, Whh2f, b2f,
                                                Wih2b, Whh2b, b2b, W2, out);
    }
}

// Round 7
// 1068.523 us; speedup vs baseline: 1.0877x; 1.0022x over previous
//
#include <hip/hip_runtime.h>

#define T_LEN 4096
#define B_SZ  256

typedef float v2f __attribute__((ext_vector_type(2)));
typedef float v4f __attribute__((ext_vector_type(4)));

__device__ __forceinline__ float fexp2(float x) { return __builtin_amdgcn_exp2f(x); }
__device__ __forceinline__ float frcp(float x)  { return __builtin_amdgcn_rcpf(x); }

// DPP row_ror:S (S=1..15): lane l <- lane (l-S)&15 within its 16-lane row.
template<int S>
__device__ __forceinline__ float rorN(float v) {
    return __int_as_float(__builtin_amdgcn_update_dpp(
        0, __float_as_int(v), 0x120 + S, 0xf, 0xf, true));
}

// Inline-asm vm ops: RA cannot rematerialize an asm result (plain loads were
// re-emitted at uses, exposing full latency), and the asm vm stream keeps
// the outstanding-op counts for manual s_waitcnt exact.
template<int OFF>
__device__ __forceinline__ v4f aload(const float* p) {
    v4f r;
    asm volatile("global_load_dwordx4 %0, %1, off offset:%2"
                 : "=v"(r) : "v"(p), "i"(OFF) : "memory");
    return r;
}
__device__ __forceinline__ void aatomic(float* p, float v) {
    unsafeAtomicAdd(p, v);   // global_atomic_add_f32, no-return (result dead)
}
__device__ __forceinline__ void astore(float* p, float v) {
    asm volatile("global_store_dword %0, %1, off" :: "v"(p), "v"(v) : "memory");
}

// ---------------------------------------------------------------------------
// Fallback-path init: y1 <- bl1 broadcast, out <- bl2 broadcast.
// ---------------------------------------------------------------------------
__global__ void init_bias_kernel(const float* __restrict__ bl1,
                                 const float* __restrict__ bl2,
                                 float* __restrict__ y1,
                                 float* __restrict__ out)
{
    const long idx = (long)blockIdx.x * blockDim.x + threadIdx.x; // over B*T
    float4 a1 = make_float4(bl1[0], bl1[1], bl1[2], bl1[3]);
    float4 b1 = make_float4(bl1[4], bl1[5], bl1[6], bl1[7]);
    float4 a2 = make_float4(bl2[0], bl2[1], bl2[2], bl2[3]);
    float4 b2 = make_float4(bl2[4], bl2[5], bl2[6], bl2[7]);
    float4* y4 = (float4*)y1;
    float4* o4 = (float4*)out;
    y4[idx * 2 + 0] = a1;
    y4[idx * 2 + 1] = b1;
    o4[idx * 2 + 0] = a2;
    o4[idx * 2 + 1] = b2;
}

// ---------------------------------------------------------------------------
// Dense output projection y[b,t,:] = Hf@Wf^T + Hb@Wb^T + bl. One thread per
// (b,t) row. Hb/yo may ALIAS (final kernel runs in-place over d_out) -> no
// __restrict__ on those two; loads are emitted before stores (own row only).
// ---------------------------------------------------------------------------
__global__ void proj_kernel(const float* __restrict__ Hf,
                            const float* Hb,
                            const float* __restrict__ W,   // [8,16]
                            const float* __restrict__ bl,  // [8]
                            float* yo)
{
    const long idx = (long)blockIdx.x * blockDim.x + threadIdx.x; // over B*T
    const float4* f4 = (const float4*)(Hf + idx * 8);
    const float4* b4 = (const float4*)(Hb + idx * 8);
    float4 fa = f4[0], fb = f4[1];
    float4 ba = b4[0], bb = b4[1];
    float o[8];
    #pragma unroll
    for (int d = 0; d < 8; ++d) {
        float s = bl[d];
        s = fmaf(fa.x, W[d * 16 + 0], s);
        s = fmaf(fa.y, W[d * 16 + 1], s);
        s = fmaf(fa.z, W[d * 16 + 2], s);
        s = fmaf(fa.w, W[d * 16 + 3], s);
        s = fmaf(fb.x, W[d * 16 + 4], s);
        s = fmaf(fb.y, W[d * 16 + 5], s);
        s = fmaf(fb.z, W[d * 16 + 6], s);
        s = fmaf(fb.w, W[d * 16 + 7], s);
        s = fmaf(ba.x, W[d * 16 + 8], s);
        s = fmaf(ba.y, W[d * 16 + 9], s);
        s = fmaf(ba.z, W[d * 16 + 10], s);
        s = fmaf(ba.w, W[d * 16 + 11], s);
        s = fmaf(bb.x, W[d * 16 + 12], s);
        s = fmaf(bb.y, W[d * 16 + 13], s);
        s = fmaf(bb.z, W[d * 16 + 14], s);
        s = fmaf(bb.w, W[d * 16 + 15], s);
        o[d] = s;
    }
    float4* y4 = (float4*)(yo + idx * 8);
    y4[0] = make_float4(o[0], o[1], o[2], o[3]);
    y4[1] = make_float4(o[4], o[5], o[6], o[7]);
}

// ---------------------------------------------------------------------------
// Tier-A: precompute pre-scaled input projections for BOTH directions.
// xg layout [B][T/4][16][8]: for tile tb, lane-slot cl (j=cl&7, half=cl>>3),
// entry [s*2+0] = sA*(Wih[rA].x_t + b[rA]) and [s*2+1] = sB*(Wih[rB].x_t +
// b[rB]) at t = tb*4+s. Per rec-lane per macro this is exactly 8 contiguous
// floats = two dwordx4 loads. Memory-bound (256 MB writes).
// ---------------------------------------------------------------------------
__global__ __launch_bounds__(256)
void xg_kernel(const float* __restrict__ x,      // [B,T,8]
               const float* __restrict__ WihF, const float* __restrict__ bF,
               const float* __restrict__ WihB, const float* __restrict__ bB,
               float* __restrict__ xgF, float* __restrict__ xgB)
{
    const long per = (long)B_SZ * (T_LEN / 4) * 16;
    const long gid = (long)blockIdx.x * blockDim.x + threadIdx.x;
    const int  dir = gid >= per;
    const long idx = dir ? gid - per : gid;
    const int  cl  = (int)(idx & 15);
    const long bt  = idx >> 4;              // b*(T/4) + tb
    const int  j = cl & 7, half = cl >> 3;
    const int  rA = half * 16 + j, rB = rA + 8;

    const float NL2E = -1.4426950408889634f;
    const float GSC  = 2.0f * NL2E;
    const float sA = half ? GSC : NL2E, sB = NL2E;

    const float* Wih  = dir ? WihB : WihF;
    const float* bias = dir ? bB : bF;
    float wa[8], wb[8];
    #pragma unroll
    for (int k = 0; k < 8; ++k) {
        wa[k] = Wih[rA * 8 + k] * sA;
        wb[k] = Wih[rB * 8 + k] * sB;
    }
    const float ba = bias[rA] * sA, bbv = bias[rB] * sB;

    const float* xr = x + bt * 32;          // 4 steps x 8 inputs
    float o[8];
    #pragma unroll
    for (int s = 0; s < 4; ++s) {
        const float* xs = xr + s * 8;
        float zA = ba, zB = bbv;
        #pragma unroll
        for (int k = 0; k < 8; ++k) {
            const float xv = xs[k];
            zA = fmaf(wa[k], xv, zA);
            zB = fmaf(wb[k], xv, zB);
        }
        o[s * 2 + 0] = zA;
        o[s * 2 + 1] = zB;
    }
    float4* d4 = (float4*)((dir ? xgB : xgF) + idx * 8);
    d4[0] = make_float4(o[0], o[1], o[2], o[3]);
    d4[1] = make_float4(o[4], o[5], o[6], o[7]);
}

// ---------------------------------------------------------------------------
// Tier-A recurrence: input projection PRECOMPUTED (xg). The step is nearly
// pure-chain: 7 DPP rotations, 8 fma/mul + 3 add matvec (seeded by the
// loaded xg pair), activations, one h store. Ring shrinks to 2 v4f/macro.
// vmcnt ledger (2 loads + 4 stores per macro, derived op-by-op):
// prologue 4/8/12, steady 12, epilogue 12/12/10/8.
// bwd consumes the tile's step-pairs in reverse (s=3..0) and strides -128.
// ---------------------------------------------------------------------------
template<int ST>
__device__ __forceinline__ void rec_xg_body(
    const float* xg,   // [B][T/4][16][8] tiled pre-scaled gate inputs
    const float* Whh,  // [32,8]
    float* H,          // [B,T,8] h sequence out
    int b0)            // batch of first cell in this wave
{
    const int tid  = threadIdx.x;
    const int cl   = tid & 15;
    const int j    = cl & 7;
    const int half = cl >> 3;
    const int b    = b0 + (tid >> 4);

    const int rA = half * 16 + j;        // half0: i-row j   | half1: g-row 16+j
    const int rB = half * 16 + 8 + j;    // half0: f-row 8+j | half1: o-row 24+j

    const float NL2E = -1.4426950408889634f;
    const float GSC  = 2.0f * NL2E;
    const float sA   = half ? GSC : NL2E;
    const float sB   = NL2E;
    const float aselA = half ? 2.0f : GSC;
    const float bselA = half ? -1.0f : 0.0f;

    v2f Whk[8];
    #pragma unroll
    for (int s = 0; s < 8; ++s) {
        const int k = (j - s) & 7;
        Whk[s] = (v2f){Whh[rA * 8 + k] * sA, Whh[rB * 8 + k] * sB};
    }

    const int tb0 = (ST > 0) ? 0 : (T_LEN / 4 - 1);
    const float* xp = xg + (((long)b * (T_LEN / 4) + tb0) * 16 + cl) * 8;
    const int t0 = (ST > 0) ? 0 : (T_LEN - 1);
    float* hp = H + ((long)b * T_LEN + t0) * 8 + j;

    float sc = 0.0f, h = 0.0f;   // sc = GSC * c

    auto step = [&](v2f zx) {
        // 7 independent VALU rotations of h (h_{t-1})
        float hr0 = h;
        float hr1 = rorN<1>(h);
        float hr2 = rorN<2>(h);
        float hr3 = rorN<3>(h);
        float hr4 = rorN<4>(h);
        float hr5 = rorN<5>(h);
        float hr6 = rorN<6>(h);
        float hr7 = rorN<7>(h);

        // hidden matvec seeded by the precomputed input projection
        v2f cA = __builtin_elementwise_fma(Whk[0], (v2f){hr0, hr0}, zx);
        cA = __builtin_elementwise_fma(Whk[1], (v2f){hr1, hr1}, cA);
        v2f cB = Whk[2] * (v2f){hr2, hr2};
        cB = __builtin_elementwise_fma(Whk[3], (v2f){hr3, hr3}, cB);
        v2f cC = Whk[4] * (v2f){hr4, hr4};
        cC = __builtin_elementwise_fma(Whk[5], (v2f){hr5, hr5}, cC);
        v2f cD = Whk[6] * (v2f){hr6, hr6};
        cD = __builtin_elementwise_fma(Whk[7], (v2f){hr7, hr7}, cD);
        const v2f z = (cA + cB) + (cC + cD);

        // activations: half0 vA = GSC*sigma(zi), half1 vA = tanh(zg);
        //              half0 vB = sigma(zf),     half1 vB = sigma(zo)
        const float vA = fmaf(frcp(1.0f + fexp2(z.x)), aselA, bselA);
        const float vB = frcp(1.0f + fexp2(z.y));

        const float pAx = rorN<8>(vA);
        const float pBx = rorN<8>(vB);
        const float gf = half ? pBx : vB;
        const float go = half ? vB  : pBx;

        sc = fmaf(gf, sc, vA * pAx);            // sc = GSC * c
        const float th = fmaf(frcp(1.0f + fexp2(sc)), 2.0f, -1.0f);
        h = go * th;

        astore(hp, h);         // both halves store identical value: benign
        hp += ST * 8;
    };

    v4f A0, A1, B0, B1, C0, C1;

#define LOADM2(P0, P1)                                                         \
    P0 = aload<0>(xp); P1 = aload<16>(xp); xp += ST * 128;

#define WAITM2(N, P0, P1)                                                      \
    asm volatile("s_waitcnt vmcnt(" #N ")"                                     \
        : "+v"(P0), "+v"(P1) :: "memory")

#define MACRO4X(P0, P1)                                                        \
    if constexpr (ST > 0) {                                                    \
        step((v2f){P0.x, P0.y}); step((v2f){P0.z, P0.w});                      \
        step((v2f){P1.x, P1.y}); step((v2f){P1.z, P1.w});                      \
    } else {                                                                   \
        step((v2f){P1.z, P1.w}); step((v2f){P1.x, P1.y});                      \
        step((v2f){P0.z, P0.w}); step((v2f){P0.x, P0.y});                      \
    }

    // drain compiler-issued (weight) loads so asm vm counts are exact
    asm volatile("s_waitcnt vmcnt(0)" ::: "memory");

    LOADM2(A0, A1)                     // ring fill: 3 macros lookahead
    LOADM2(B0, B1)
    LOADM2(C0, C1)
    WAITM2(4, A0, A1);  MACRO4X(A0, A1)       // M0
    LOADM2(A0, A1)
    WAITM2(8, B0, B1);  MACRO4X(B0, B1)       // M1
    LOADM2(B0, B1)
    WAITM2(12, C0, C1); MACRO4X(C0, C1)       // M2

    for (int i = 0; i < 339; ++i) {    // M3..M1019
        LOADM2(C0, C1) WAITM2(12, A0, A1); MACRO4X(A0, A1)
        LOADM2(A0, A1) WAITM2(12, B0, B1); MACRO4X(B0, B1)
        LOADM2(B0, B1) WAITM2(12, C0, C1); MACRO4X(C0, C1)
    }
    LOADM2(C0, C1)
    WAITM2(12, A0, A1); MACRO4X(A0, A1)       // M1020
    LOADM2(A0, A1)
    WAITM2(12, B0, B1); MACRO4X(B0, B1)       // M1021
    WAITM2(10, C0, C1); MACRO4X(C0, C1)       // M1022
    WAITM2(8,  A0, A1); MACRO4X(A0, A1)       // M1023

#undef LOADM2
#undef WAITM2
#undef MACRO4X
}

__global__ __launch_bounds__(64, 1)
void lstm_rec_xg_kernel(const float* __restrict__ xgF,
                        const float* __restrict__ xgB,
                        const float* __restrict__ WhhF,
                        const float* __restrict__ WhhB,
                        float* __restrict__ Hf,
                        float* __restrict__ Hb)
{
    if (blockIdx.x < 64)
        rec_xg_body<1 >(xgF, WhhF, Hf, 4 * (int)blockIdx.x);
    else
        rec_xg_body<-1>(xgB, WhhB, Hb, 4 * ((int)blockIdx.x - 64));
}

// ---------------------------------------------------------------------------
// Tier-B / fallback recurrence (proven R6/R2 structures), unchanged.
// ---------------------------------------------------------------------------
template<int ST, bool PROJ>
__device__ __forceinline__ void rec_body(
    const float* x, const float* Wih, const float* Whh, const float* bias,
    const float* Wp, int dcol, float* y, float* H, int b0)
{
    const int tid  = threadIdx.x;
    const int cl   = tid & 15;
    const int j    = cl & 7;
    const int half = cl >> 3;
    const int b    = b0 + (tid >> 4);

    const int rA = half * 16 + j;
    const int rB = half * 16 + 8 + j;

    const float NL2E = -1.4426950408889634f;
    const float GSC  = 2.0f * NL2E;
    const float sA   = half ? GSC : NL2E;
    const float sB   = NL2E;
    const float aselA = half ? 2.0f : GSC;
    const float bselA = half ? -1.0f : 0.0f;

    v2f Whk[8], Wik[8];
    float Wcp[8];
    #pragma unroll
    for (int s = 0; s < 8; ++s) {
        const int k = (j - s) & 7;
        Whk[s] = (v2f){Whh[rA * 8 + k] * sA, Whh[rB * 8 + k] * sB};
        if constexpr (PROJ)
            Wcp[s] = Wp[j * 16 + dcol + k] * 0.5f;
    }
    #pragma unroll
    for (int k = 0; k < 8; ++k)
        Wik[k] = (v2f){Wih[rA * 8 + k] * sA, Wih[rB * 8 + k] * sB};
    const v2f bpk = (v2f){bias[rA] * sA, bias[rB] * sB};

    const int start = (ST > 0) ? 0 : (T_LEN - 1);
    const float* xp = x + ((long)b * T_LEN + start) * 8;
    float* wp = nullptr;
    float* hp = nullptr;
    if constexpr (PROJ)  wp = y + ((long)b * T_LEN + start) * 8 + j;
    if constexpr (!PROJ) hp = H + ((long)b * T_LEN + start) * 8 + j;

    float sc = 0.0f, h = 0.0f;

    auto step = [&](v4f xa, v4f xb, bool doProj) {
        v2f ipA = bpk;
        ipA = __builtin_elementwise_fma(Wik[0], (v2f){xa.x, xa.x}, ipA);
        ipA = __builtin_elementwise_fma(Wik[1], (v2f){xa.y, xa.y}, ipA);
        ipA = __builtin_elementwise_fma(Wik[2], (v2f){xa.z, xa.z}, ipA);
        ipA = __builtin_elementwise_fma(Wik[3], (v2f){xa.w, xa.w}, ipA);
        v2f ipB = Wik[4] * (v2f){xb.x, xb.x};
        ipB = __builtin_elementwise_fma(Wik[5], (v2f){xb.y, xb.y}, ipB);
        ipB = __builtin_elementwise_fma(Wik[6], (v2f){xb.z, xb.z}, ipB);
        ipB = __builtin_elementwise_fma(Wik[7], (v2f){xb.w, xb.w}, ipB);

        float hr0 = h;
        float hr1 = rorN<1>(h);
        float hr2 = rorN<2>(h);
        float hr3 = rorN<3>(h);
        float hr4 = rorN<4>(h);
        float hr5 = rorN<5>(h);
        float hr6 = rorN<6>(h);
        float hr7 = rorN<7>(h);

        v2f cA = __builtin_elementwise_fma(Whk[0], (v2f){hr0, hr0}, ipA);
        cA = __builtin_elementwise_fma(Whk[1], (v2f){hr1, hr1}, cA);
        v2f cB = __builtin_elementwise_fma(Whk[2], (v2f){hr2, hr2}, ipB);
        cB = __builtin_elementwise_fma(Whk[3], (v2f){hr3, hr3}, cB);
        v2f cC = Whk[4] * (v2f){hr4, hr4};
        cC = __builtin_elementwise_fma(Whk[5], (v2f){hr5, hr5}, cC);
        v2f cD = Whk[6] * (v2f){hr6, hr6};
        cD = __builtin_elementwise_fma(Whk[7], (v2f){hr7, hr7}, cD);
        const v2f z = (cA + cB) + (cC + cD);

        if constexpr (PROJ) {
            if (doProj) {
                float pa = hr0 * Wcp[0];
                pa = fmaf(hr1, Wcp[1], pa);
                pa = fmaf(hr2, Wcp[2], pa);
                pa = fmaf(hr3, Wcp[3], pa);
                pa = fmaf(hr4, Wcp[4], pa);
                pa = fmaf(hr5, Wcp[5], pa);
                pa = fmaf(hr6, Wcp[6], pa);
                pa = fmaf(hr7, Wcp[7], pa);
                aatomic(wp, pa);
                wp += ST * 8;
            }
        }

        const float vA = fmaf(frcp(1.0f + fexp2(z.x)), aselA, bselA);
        const float vB = frcp(1.0f + fexp2(z.y));

        const float pAx = rorN<8>(vA);
        const float pBx = rorN<8>(vB);
        const float gf = half ? pBx : vB;
        const float go = half ? vB  : pBx;

        sc = fmaf(gf, sc, vA * pAx);
        const float th = fmaf(frcp(1.0f + fexp2(sc)), 2.0f, -1.0f);
        h = go * th;

        if constexpr (!PROJ) {
            astore(hp, h);
            hp += ST * 8;
        }
    };

    v4f A0, A1, A2, A3, A4, A5, A6, A7;
    v4f B0, B1, B2, B3, B4, B5, B6, B7;
    v4f C0, C1, C2, C3, C4, C5, C6, C7;

#define AREGS A0, A1, A2, A3, A4, A5, A6, A7
#define BREGS B0, B1, B2, B3, B4, B5, B6, B7
#define CREGS C0, C1, C2, C3, C4, C5, C6, C7

#define LOADM_I(P0, P1, P2, P3, P4, P5, P6, P7)                                \
    P0 = aload<0>(xp);            P1 = aload<16>(xp);                          \
    P2 = aload<ST * 32>(xp);      P3 = aload<ST * 32 + 16>(xp);                \
    P4 = aload<ST * 64>(xp);      P5 = aload<ST * 64 + 16>(xp);                \
    P6 = aload<ST * 96>(xp);      P7 = aload<ST * 96 + 16>(xp);                \
    xp += ST * 32;
#define LOADM(REGS) LOADM_I(REGS)

#define WAITM_I(N, P0, P1, P2, P3, P4, P5, P6, P7)                             \
    asm volatile("s_waitcnt vmcnt(" #N ")"                                     \
        : "+v"(P0), "+v"(P1), "+v"(P2), "+v"(P3),                              \
          "+v"(P4), "+v"(P5), "+v"(P6), "+v"(P7) :: "memory")
#define WAITM(N, REGS) WAITM_I(N, REGS)

#define MACRO4_I(P0, P1, P2, P3, P4, P5, P6, P7, FIRSTPROJ)                    \
    step(P0, P1, FIRSTPROJ);                                                   \
    step(P2, P3, true);                                                        \
    step(P4, P5, true);                                                        \
    step(P6, P7, true);
#define MACRO4(REGS, FIRSTPROJ) MACRO4_I(REGS, FIRSTPROJ)

    asm volatile("s_waitcnt vmcnt(0)" ::: "memory");

    LOADM(AREGS)
    LOADM(BREGS)
    LOADM(CREGS)

    if constexpr (PROJ) {
        WAITM(16, AREGS); MACRO4(AREGS, false)
        LOADM(AREGS)
        WAITM(19, BREGS); MACRO4(BREGS, true)
        LOADM(BREGS)
        WAITM(23, CREGS); MACRO4(CREGS, true)
    } else {
        WAITM(16, AREGS); MACRO4(AREGS, true)
        LOADM(AREGS)
        WAITM(20, BREGS); MACRO4(BREGS, true)
        LOADM(BREGS)
        WAITM(24, CREGS); MACRO4(CREGS, true)
    }

    for (int i = 0; i < 339; ++i) {
        LOADM(CREGS) WAITM(24, AREGS); MACRO4(AREGS, true)
        LOADM(AREGS) WAITM(24, BREGS); MACRO4(BREGS, true)
        LOADM(BREGS) WAITM(24, CREGS); MACRO4(CREGS, true)
    }
    LOADM(CREGS)
    WAITM(24, AREGS); MACRO4(AREGS, true)
    LOADM(AREGS)
    WAITM(24, BREGS); MACRO4(BREGS, true)
    WAITM(16, CREGS); MACRO4(CREGS, true)
    WAITM(8,  AREGS); MACRO4(AREGS, true)

#undef LOADM
#undef LOADM_I
#undef MACRO4
#undef MACRO4_I
#undef WAITM
#undef WAITM_I
#undef AREGS
#undef BREGS
#undef CREGS

    if constexpr (PROJ) {
        float pa = h * Wcp[0];
        pa = fmaf(rorN<1>(h), Wcp[1], pa);
        pa = fmaf(rorN<2>(h), Wcp[2], pa);
        pa = fmaf(rorN<3>(h), Wcp[3], pa);
        pa = fmaf(rorN<4>(h), Wcp[4], pa);
        pa = fmaf(rorN<5>(h), Wcp[5], pa);
        pa = fmaf(rorN<6>(h), Wcp[6], pa);
        pa = fmaf(rorN<7>(h), Wcp[7], pa);
        aatomic(wp, pa);
    }
}

__global__ __launch_bounds__(64, 1)
void lstm_rec_kernel(const float* __restrict__ x,
                     const float* __restrict__ WihF, const float* __restrict__ WhhF,
                     const float* __restrict__ bF,
                     const float* __restrict__ WihB, const float* __restrict__ WhhB,
                     const float* __restrict__ bB,
                     const float* __restrict__ Wp,
                     float* __restrict__ y)
{
    if (blockIdx.x < 64)
        rec_body<1,  true>(x, WihF, WhhF, bF, Wp, 0, y, nullptr, 4 * (int)blockIdx.x);
    else
        rec_body<-1, true>(x, WihB, WhhB, bB, Wp, 8, y, nullptr, 4 * ((int)blockIdx.x - 64));
}

__global__ __launch_bounds__(64, 1)
void lstm_rec_np_kernel(const float* __restrict__ x,
                        const float* __restrict__ WihF, const float* __restrict__ WhhF,
                        const float* __restrict__ bF,
                        const float* __restrict__ WihB, const float* __restrict__ WhhB,
                        const float* __restrict__ bB,
                        float* __restrict__ Hf,
                        float* __restrict__ Hb)
{
    if (blockIdx.x < 64)
        rec_body<1,  false>(x, WihF, WhhF, bF, nullptr, 0, nullptr, Hf, 4 * (int)blockIdx.x);
    else
        rec_body<-1, false>(x, WihB, WhhB, bB, nullptr, 0, nullptr, Hb, 4 * ((int)blockIdx.x - 64));
}

extern "C" void kernel_launch(void* const* d_in, const int* in_sizes, int n_in,
                              void* d_out, int out_size, void* d_ws, size_t ws_size,
                              hipStream_t stream)
{
    const float* x     = (const float*)d_in[0];
    const float* Wih1f = (const float*)d_in[1];
    const float* Whh1f = (const float*)d_in[2];
    const float* b1f   = (const float*)d_in[3];
    const float* Wih1b = (const float*)d_in[4];
    const float* Whh1b = (const float*)d_in[5];
    const float* b1b   = (const float*)d_in[6];
    const float* Wih2f = (const float*)d_in[7];
    const float* Whh2f = (const float*)d_in[8];
    const float* b2f   = (const float*)d_in[9];
    const float* Wih2b = (const float*)d_in[10];
    const float* Whh2b = (const float*)d_in[11];
    const float* b2b   = (const float*)d_in[12];
    const float* W1    = (const float*)d_in[13];
    const float* bl1   = (const float*)d_in[14];
    const float* W2    = (const float*)d_in[15];
    const float* bl2   = (const float*)d_in[16];

    float* out = (float*)d_out;
    const int BT = B_SZ * T_LEN;
    const size_t MB32 = (size_t)32 * 1024 * 1024;

    if (ws_size >= 10 * MB32) {
        // Tier A: precomputed input projections (xg) + near-pure-chain rec.
        float* xgF = (float*)d_ws;                      // 128 MB
        float* xgB = (float*)((char*)d_ws + 4 * MB32);  // 128 MB
        float* Hf  = (float*)((char*)d_ws + 8 * MB32);  //  32 MB
        float* y1  = (float*)((char*)d_ws + 9 * MB32);  //  32 MB
        float* Hb  = out;                               // borrow (32 MB)
        const int XGB = (int)(2L * B_SZ * (T_LEN / 4) * 16 / 256);  // 32768

        xg_kernel<<<XGB, 256, 0, stream>>>(x, Wih1f, b1f, Wih1b, b1b, xgF, xgB);
        lstm_rec_xg_kernel<<<128, 64, 0, stream>>>(xgF, xgB, Whh1f, Whh1b, Hf, Hb);
        proj_kernel<<<BT / 256, 256, 0, stream>>>(Hf, Hb, W1, bl1, y1);
        xg_kernel<<<XGB, 256, 0, stream>>>(y1, Wih2f, b2f, Wih2b, b2b, xgF, xgB);
        lstm_rec_xg_kernel<<<128, 64, 0, stream>>>(xgF, xgB, Whh2f, Whh2b, Hf, Hb);
        proj_kernel<<<BT / 256, 256, 0, stream>>>(Hf, Hb, W2, bl2, out);  // in-place
    } else if (ws_size >= 2 * MB32) {
        // Tier B (proven 1071 us): raw-h rec + separate projections.
        float* ws0 = (float*)d_ws;
        float* ws1 = (float*)((char*)d_ws + MB32);
        float* Hb  = out;

        lstm_rec_np_kernel<<<128, 64, 0, stream>>>(x, Wih1f, Whh1f, b1f,
                                                   Wih1b, Whh1b, b1b, ws0, Hb);
        proj_kernel<<<BT / 256, 256, 0, stream>>>(ws0, Hb, W1, bl1, ws1);
        lstm_rec_np_kernel<<<128, 64, 0, stream>>>(ws1, Wih2f, Whh2f, b2f,
                                                   Wih2b, Whh2b, b2b, ws0, Hb);
        proj_kernel<<<BT / 256, 256, 0, stream>>>(ws0, Hb, W2, bl2, out);
    } else {
        // Proven fallback (1098 us): fused atomic projection.
        float* y1 = (float*)d_ws;

        init_bias_kernel<<<BT / 256, 256, 0, stream>>>(bl1, bl2, y1, out);
        lstm_rec_kernel<<<128, 64, 0, stream>>>(x, Wih1f, Whh1f, b1f,
                                                Wih1b, Whh1b, b1b, W1, y1);
        lstm_rec_kernel<<<128, 64, 0, stream>>>(y1, Wih2f, Whh2f, b2f,
                                                Wih2b, Whh2b, b2b, W2, out);
    }
}